// Round 11
// baseline (560.265 us; speedup 1.0000x reference)
//
#include <hip/hip_runtime.h>
#include <cstdint>
#include <cstddef>

// Conv2d 3x3 s1 p1: N=16, CI=64, CO=128, H=W=224, fp32 in/out.
// v11: v10 anchor (passing, 244 us) with re-decomposed waves in conv3:
// 8 waves = 2(hr) x 2(mh: 64-co half) x 2(nh: w 64/48 split), wave tile
// 64co x 64/48w, acc[4][<=4]. Each B-frag ds_read_b128 now feeds 4 MFMA
// (was 2) -> per-CU compute LDS reads halved (1008 -> 504 per step).
// Epilogue adapted: per-wave [16co][68] bounce, contiguous float4 stores.
// Staging/ring/sync structure byte-identical to v10.

typedef short bf16x8 __attribute__((ext_vector_type(8)));
typedef float f32x4 __attribute__((ext_vector_type(4)));

template<int V> struct IC { static constexpr int value = V; };

#define N_ 16
#define CI_ 64
#define CO_ 128
#define H_ 224
#define W_ 224
#define HW_ (H_ * W_)

// xp strides in shorts
#define WP_ 226
#define CBS_ 1808ULL        // WP_*8
#define HPS_ 14464ULL       // 8*CBS_
#define NS_ 3268864ULL      // 226*HPS_

#define ROWBUF_SHORTS 7296  // 8cb * 114wp * 8ci
#define CONV3_LDS 145408    // 6*7296*2 + bounce (8*1088*4 = 34816 used)

__device__ __forceinline__ unsigned short f2bf(float f) {
    unsigned u = __builtin_bit_cast(unsigned, f);
    u += 0x7FFFu + ((u >> 16) & 1u);   // round-to-nearest-even
    return (unsigned short)(u >> 16);
}

// weight [CO][CI][3][3] fp32 -> wr[t][co][ci] bf16  (t = kh*3+kw)
__global__ void prep_weight(const float* __restrict__ w, unsigned short* __restrict__ wr) {
    int i = blockIdx.x * 256 + threadIdx.x;          // i = t*8192 + co*64 + ci
    if (i >= 9 * CO_ * CI_) return;
    int ci = i & 63;
    int co = (i >> 6) & 127;
    int t  = i >> 13;
    wr[i] = f2bf(w[(co * CI_ + ci) * 9 + t]);
}

// x[n][ci][h][w] fp32 -> xp[n][hp][cb][wp][c8] bf16, halos (hp 0/225, wp 0/225) zero.
__global__ __launch_bounds__(256) void prep_x(const float* __restrict__ x,
                                              unsigned short* __restrict__ xp) {
    int b = blockIdx.x;                 // 16*226
    int n = b / 226, hp = b - n * 226;
    int tid = threadIdx.x;
    unsigned short* row = xp + (size_t)n * NS_ + (size_t)hp * HPS_;
    if (hp == 0 || hp == 225) {
        #pragma unroll
        for (int k = 0; k < 8; ++k) {
            int i = k * 256 + tid;
            if (i < 1808) ((uint4*)row)[i] = make_uint4(0, 0, 0, 0);
        }
        return;
    }
    int h = hp - 1;
    const float* xb = x + (size_t)n * CI_ * HW_ + (size_t)h * W_;
    for (int k = 0; k < 7; ++k) {
        int item = k * 256 + tid;       // 1792 = 8cb * 224w
        int w = item % 224;
        int cb = item / 224;
        unsigned r[4];
        #pragma unroll
        for (int c = 0; c < 4; ++c) {
            float lo = xb[(size_t)(cb * 8 + 2 * c) * HW_ + w];
            float hi = xb[(size_t)(cb * 8 + 2 * c + 1) * HW_ + w];
            r[c] = (unsigned)f2bf(lo) | ((unsigned)f2bf(hi) << 16);
        }
        *(uint4*)(row + (size_t)cb * CBS_ + (size_t)(w + 1) * 8) = make_uint4(r[0], r[1], r[2], r[3]);
    }
    if (tid < 16) {
        int cb = tid >> 1, wp = (tid & 1) * 225;
        *(uint4*)(row + (size_t)cb * CBS_ + (size_t)wp * 8) = make_uint4(0, 0, 0, 0);
    }
}

// v11 main: persistent strip, 6-slot ring. 8 waves: hr=wid&1, mh=(wid>>1)&1,
// nh=wid>>2. Wave tile 64co x (nh==0 ? 64 : 48) w. acc[4][<=4] f32x4.
__global__ __launch_bounds__(512, 2) void conv3(
    const unsigned short* __restrict__ xp, const unsigned short* __restrict__ wr,
    const float* __restrict__ bias, float* __restrict__ out)
{
    extern __shared__ __align__(16) unsigned short ring[];  // [6][7296] shorts + bounce
    float* bounce = (float*)ring + 6 * ROWBUF_SHORTS / 2;   // 21888 floats in; 8x1088 used

    int bid = blockIdx.x;
    int swz = (bid & 7) * 32 + (bid >> 3);     // bijective over 256, XCD-chunked
    int n = swz >> 4;
    int rem = swz & 15;
    int wseg = rem & 1;
    int strip = rem >> 1;
    int ho0 = strip * 28;
    int w0 = wseg * 112;

    int tid = threadIdx.x, lane = tid & 63, wid = tid >> 6;
    int hr = wid & 1, mh = (wid >> 1) & 1, nh = wid >> 2;
    int lrow = lane & 15, lk = lane >> 4;

    const unsigned short* xpn = xp + (size_t)n * NS_;

    // hoisted bias for this wave's 64-co half
    float bv[4][4];
    #pragma unroll
    for (int mf = 0; mf < 4; ++mf)
        #pragma unroll
        for (int r = 0; r < 4; ++r)
            bv[mf][r] = bias[mh * 64 + mf * 16 + lk * 4 + r];

    // stage one xp row (912 x 16B chunks) into its ring slot; dst linear in tid.
    auto stage_row = [&](int hp) {
        const unsigned short* srow = xpn + (size_t)hp * HPS_ + (size_t)w0 * 8;
        unsigned short* dbase = ring + (size_t)(hp % 6) * ROWBUF_SHORTS;
        int idx = tid;
        {
            int cb = idx / 114, wp = idx - cb * 114;
            __builtin_amdgcn_global_load_lds(
                (const __attribute__((address_space(1))) void*)(srow + (size_t)cb * CBS_ + (size_t)wp * 8),
                (__attribute__((address_space(3))) void*)(dbase + (size_t)idx * 8), 16, 0, 0);
        }
        idx = 512 + tid;
        if (idx < 912) {
            int cb = idx / 114, wp = idx - cb * 114;
            __builtin_amdgcn_global_load_lds(
                (const __attribute__((address_space(1))) void*)(srow + (size_t)cb * CBS_ + (size_t)wp * 8),
                (__attribute__((address_space(3))) void*)(dbase + (size_t)idx * 8), 16, 0, 0);
        }
    };

    // prologue: rows ho0..ho0+3
    stage_row(ho0); stage_row(ho0 + 1); stage_row(ho0 + 2); stage_row(ho0 + 3);
    __syncthreads();

    #pragma unroll 1
    for (int i = 0; i < 14; ++i) {
        int ho = ho0 + 2 * i;

        // 1) prefetch next step's two new rows into the (dead) slots
        if (i < 13) { stage_row(ho + 4); stage_row(ho + 5); }

        // 2+3) compute + epilogue (no barriers inside; wave-divergent on nh)
        auto body = [&](auto NFC_) {
            constexpr int NFC = decltype(NFC_)::value;   // 4 (nh=0) or 3 (nh=1)
            f32x4 acc[4][NFC];
            #pragma unroll
            for (int a = 0; a < 4; ++a)
                #pragma unroll
                for (int b2 = 0; b2 < NFC; ++b2)
                    #pragma unroll
                    for (int k = 0; k < 4; ++k)
                        acc[a][b2][k] = 0.0f;

            #pragma unroll
            for (int ch = 0; ch < 2; ++ch) {
                #pragma unroll
                for (int t = 0; t < 9; ++t) {
                    int kh = t / 3, kw = t - kh * 3;
                    bf16x8 afr[4];
                    #pragma unroll
                    for (int mf = 0; mf < 4; ++mf) {
                        size_t ai = ((size_t)(t * 128 + mh * 64 + mf * 16 + lrow)) * 64
                                  + (size_t)(ch * 32 + lk * 8);
                        afr[mf] = *(const bf16x8*)(wr + ai);
                    }
                    int slot = (ho + hr + kh) % 6;
                    int rb = slot * ROWBUF_SHORTS + ((ch * 4 + lk) * 114) * 8;
                    int wpb = nh * 64 + lrow + kw;
                    #pragma unroll
                    for (int nf = 0; nf < NFC; ++nf) {
                        bf16x8 bfr = *(const bf16x8*)(ring + rb + (size_t)(wpb + nf * 16) * 8);
                        #pragma unroll
                        for (int mf = 0; mf < 4; ++mf)
                            acc[mf][nf] = __builtin_amdgcn_mfma_f32_16x16x32_bf16(
                                afr[mf], bfr, acc[mf][nf], 0, 0, 0);
                    }
                }
            }

            // epilogue: per-wave [16co][68] bounce -> contiguous float4 stores
            float* bw = bounce + wid * 1088;
            int h = ho + hr;
            constexpr int ROUNDS = (NFC == 4) ? 4 : 3;   // 16co*NFC*16w /4 /64
            constexpr int WQ     = (NFC == 4) ? 16 : 12; // float4 per co row
            #pragma unroll
            for (int mf = 0; mf < 4; ++mf) {
                #pragma unroll
                for (int r = 0; r < 4; ++r)
                    #pragma unroll
                    for (int nf = 0; nf < NFC; ++nf)
                        bw[(lk * 4 + r) * 68 + nf * 16 + lrow] = acc[mf][nf][r] + bv[mf][r];
                // wave-local LDS: DS ops in-order per wave, no barrier needed
                #pragma unroll
                for (int j = 0; j < ROUNDS; ++j) {
                    int idx4 = j * 64 + lane;            // < 16*WQ, all lanes active
                    int c16 = idx4 / WQ;                 // co_local 0..15
                    int w4  = idx4 - c16 * WQ;           // 0..WQ-1
                    f32x4 v = *(const f32x4*)(bw + c16 * 68 + w4 * 4);
                    size_t ob = (((size_t)n * CO_ + (mh * 64 + mf * 16 + c16)) * H_ + h) * W_
                              + w0 + nh * 64 + w4 * 4;
                    *(f32x4*)(out + ob) = v;
                }
            }
        };
        if (nh == 0) body(IC<4>{}); else body(IC<3>{});

        // 4) counted barrier: per-wave FIFO = [<=4 ring DMAs][12-16 stores];
        //    vmcnt(12) drains every wave's DMAs (publishes ring) while most
        //    output stores stay in flight across the barrier.
        __builtin_amdgcn_sched_barrier(0);
        asm volatile("s_waitcnt vmcnt(12) lgkmcnt(0)" ::: "memory");
        __builtin_amdgcn_s_barrier();
        __builtin_amdgcn_sched_barrier(0);
    }
}

// ---------------- fallback (used only if dynamic-LDS attribute fails) ----------------
__global__ __launch_bounds__(256, 2) void conv2(
    const unsigned short* __restrict__ xp, const unsigned short* __restrict__ wr,
    const float* __restrict__ bias, float* __restrict__ out)
{
    __shared__ __align__(16) unsigned short xs[4 * 8 * 114 * 8];

    int bid = blockIdx.x;
    int swz = (bid & 7) * 448 + (bid >> 3);
    int n = swz / 224;
    int r2 = swz - n * 224;
    int hblk = r2 >> 1;
    int wseg = r2 & 1;
    int h0 = hblk * 2;

    int tid = threadIdx.x, lane = tid & 63, wid = tid >> 6;
    int hr = wid & 1, mh = wid >> 1;
    int lrow = lane & 15, lk = lane >> 4;

    f32x4 acc[4][7];
    #pragma unroll
    for (int a = 0; a < 4; ++a)
        #pragma unroll
        for (int b2 = 0; b2 < 7; ++b2)
            #pragma unroll
            for (int k = 0; k < 4; ++k)
                acc[a][b2][k] = 0.0f;

    const unsigned short* xpn = xp + (size_t)n * NS_;

    #pragma unroll
    for (int it = 0; it < 14; ++it) {
        int idx = it * 256 + tid;
        int wp = idx % 114;
        int rc = idx / 114;
        const unsigned short* src = xpn + (size_t)(h0 + (rc >> 3)) * HPS_
                                  + (size_t)(rc & 7) * CBS_ + (size_t)(wseg * 112 + wp) * 8;
        __builtin_amdgcn_global_load_lds(
            (const __attribute__((address_space(1))) void*)src,
            (__attribute__((address_space(3))) void*)(xs + (size_t)idx * 8), 16, 0, 0);
    }
    if (tid < 64) {
        int idx = 3584 + tid;
        int wp = idx % 114;
        int rc = idx / 114;
        const unsigned short* src = xpn + (size_t)(h0 + (rc >> 3)) * HPS_
                                  + (size_t)(rc & 7) * CBS_ + (size_t)(wseg * 112 + wp) * 8;
        __builtin_amdgcn_global_load_lds(
            (const __attribute__((address_space(1))) void*)src,
            (__attribute__((address_space(3))) void*)(xs + (size_t)idx * 8), 16, 0, 0);
    }
    __syncthreads();

    #pragma unroll
    for (int ch = 0; ch < 2; ++ch) {
        #pragma unroll
        for (int t = 0; t < 9; ++t) {
            int kh = t / 3, kw = t - kh * 3;
            bf16x8 afr[4];
            #pragma unroll
            for (int mf = 0; mf < 4; ++mf) {
                size_t ai = ((size_t)(t * 128 + mh * 64 + mf * 16 + lrow)) * 64
                          + (size_t)(ch * 32 + lk * 8);
                afr[mf] = *(const bf16x8*)(wr + ai);
            }
            int rbase = ((hr + kh) * 8 + ch * 4 + lk) * 114;
            int wpb = lrow + kw;
            #pragma unroll
            for (int nf = 0; nf < 7; ++nf) {
                bf16x8 bfr = *(const bf16x8*)(&xs[(size_t)(rbase + wpb + nf * 16) * 8]);
                #pragma unroll
                for (int mf = 0; mf < 4; ++mf)
                    acc[mf][nf] = __builtin_amdgcn_mfma_f32_16x16x32_bf16(
                        afr[mf], bfr, acc[mf][nf], 0, 0, 0);
            }
        }
    }

    __syncthreads();
    float* lf = (float*)xs;
    int h = h0 + hr;
    #pragma unroll
    for (int mf = 0; mf < 4; ++mf) {
        float bv[4];
        #pragma unroll
        for (int r = 0; r < 4; ++r)
            bv[r] = bias[mh * 64 + mf * 16 + lk * 4 + r];
        float* wbase = lf + wid * 1808 + lk * 452 + lrow;
        #pragma unroll
        for (int r = 0; r < 4; ++r)
            #pragma unroll
            for (int nf = 0; nf < 7; ++nf)
                wbase[r * 112 + nf * 16] = acc[mf][nf][r] + bv[r];
        #pragma unroll
        for (int j = 0; j < 7; ++j) {
            int idx4 = j * 64 + lane;
            int col = idx4 / 28;
            int w4  = idx4 - col * 28;
            f32x4 v = *(const f32x4*)(lf + wid * 1808 + (col >> 2) * 452 + (col & 3) * 112 + w4 * 4);
            size_t ob = (((size_t)n * CO_ + mh * 64 + mf * 16 + col) * H_ + h) * W_
                      + wseg * 112 + w4 * 4;
            *(f32x4*)(out + ob) = v;
        }
    }
}

extern "C" void kernel_launch(void* const* d_in, const int* in_sizes, int n_in,
                              void* d_out, int out_size, void* d_ws, size_t ws_size,
                              hipStream_t stream) {
    const float* x    = (const float*)d_in[0];
    const float* w    = (const float*)d_in[1];
    const float* bias = (const float*)d_in[2];
    float* out = (float*)d_out;
    unsigned short* wr = (unsigned short*)d_ws;          // 147,456 B
    const size_t xp_bytes = (size_t)N_ * NS_ * 2;        // 104,603,648 B
    const size_t need = 147456 + xp_bytes;

    prep_weight<<<dim3(288), dim3(256), 0, stream>>>(w, wr);
    if (ws_size >= need) {
        unsigned short* xp = wr + 73728;                 // +147,456 B
        prep_x<<<dim3(16 * 226), dim3(256), 0, stream>>>(x, xp);
        hipError_t e = hipFuncSetAttribute(
            reinterpret_cast<const void*>(conv3),
            hipFuncAttributeMaxDynamicSharedMemorySize, CONV3_LDS);
        if (e == hipSuccess) {
            conv3<<<dim3(256), dim3(512), CONV3_LDS, stream>>>(xp, wr, bias, out);
        } else {
            conv2<<<dim3(16 * 112 * 2), dim3(256), 0, stream>>>(xp, wr, bias, out);
        }
    }
}

// Round 12
// 246.383 us; speedup vs baseline: 2.2740x; 2.2740x over previous
//
#include <hip/hip_runtime.h>
#include <cstdint>
#include <cstddef>

// Conv2d 3x3 s1 p1: N=16, CI=64, CO=128, H=W=224, fp32 in/out.
// v12: v10 anchor (passing, 244 us) + two local conv3 edits:
//  (1) A-fragments (step-invariant) hoisted into registers once per kernel:
//      36 x bf16x8 = 144 VGPR. Removes 288 global-load instrs per step per CU.
//      Occupancy unchanged (LDS already caps at 8 waves/CU; ~240 VGPR < 256 budget).
//  (2) epilogue bounce lk-stride 452 -> 464 floats (byte stride ≡ 64 mod 128):
//      balanced 2-way bank access (free) instead of 4-way unbalanced.
// Everything else (staging, ring, counted-vmcnt barrier, epilogue indices,
// prep_weight/prep_x, fallback) byte-identical to v10.

typedef short bf16x8 __attribute__((ext_vector_type(8)));
typedef float f32x4 __attribute__((ext_vector_type(4)));

#define N_ 16
#define CI_ 64
#define CO_ 128
#define H_ 224
#define W_ 224
#define HW_ (H_ * W_)

// xp strides in shorts
#define WP_ 226
#define CBS_ 1808ULL        // WP_*8
#define HPS_ 14464ULL       // 8*CBS_
#define NS_ 3268864ULL      // 226*HPS_

#define ROWBUF_SHORTS 7296  // 8cb * 114wp * 8ci
#define BOUNCE_WAVE_F 1840  // floats per wave: 3*464 + 3*112 + 112 headroom
#define CONV3_LDS 146432    // 6*7296*2 + 8*1840*4

__device__ __forceinline__ unsigned short f2bf(float f) {
    unsigned u = __builtin_bit_cast(unsigned, f);
    u += 0x7FFFu + ((u >> 16) & 1u);   // round-to-nearest-even
    return (unsigned short)(u >> 16);
}

// weight [CO][CI][3][3] fp32 -> wr[t][co][ci] bf16  (t = kh*3+kw)
__global__ void prep_weight(const float* __restrict__ w, unsigned short* __restrict__ wr) {
    int i = blockIdx.x * 256 + threadIdx.x;          // i = t*8192 + co*64 + ci
    if (i >= 9 * CO_ * CI_) return;
    int ci = i & 63;
    int co = (i >> 6) & 127;
    int t  = i >> 13;
    wr[i] = f2bf(w[(co * CI_ + ci) * 9 + t]);
}

// x[n][ci][h][w] fp32 -> xp[n][hp][cb][wp][c8] bf16, halos (hp 0/225, wp 0/225) zero.
__global__ __launch_bounds__(256) void prep_x(const float* __restrict__ x,
                                              unsigned short* __restrict__ xp) {
    int b = blockIdx.x;                 // 16*226
    int n = b / 226, hp = b - n * 226;
    int tid = threadIdx.x;
    unsigned short* row = xp + (size_t)n * NS_ + (size_t)hp * HPS_;
    if (hp == 0 || hp == 225) {
        #pragma unroll
        for (int k = 0; k < 8; ++k) {
            int i = k * 256 + tid;
            if (i < 1808) ((uint4*)row)[i] = make_uint4(0, 0, 0, 0);
        }
        return;
    }
    int h = hp - 1;
    const float* xb = x + (size_t)n * CI_ * HW_ + (size_t)h * W_;
    for (int k = 0; k < 7; ++k) {
        int item = k * 256 + tid;       // 1792 = 8cb * 224w
        int w = item % 224;
        int cb = item / 224;
        unsigned r[4];
        #pragma unroll
        for (int c = 0; c < 4; ++c) {
            float lo = xb[(size_t)(cb * 8 + 2 * c) * HW_ + w];
            float hi = xb[(size_t)(cb * 8 + 2 * c + 1) * HW_ + w];
            r[c] = (unsigned)f2bf(lo) | ((unsigned)f2bf(hi) << 16);
        }
        *(uint4*)(row + (size_t)cb * CBS_ + (size_t)(w + 1) * 8) = make_uint4(r[0], r[1], r[2], r[3]);
    }
    if (tid < 16) {
        int cb = tid >> 1, wp = (tid & 1) * 225;
        *(uint4*)(row + (size_t)cb * CBS_ + (size_t)wp * 8) = make_uint4(0, 0, 0, 0);
    }
}

// v12 main: persistent strip. 8 waves: hr = wid&1 (out row), mq = wid>>1 (co quarter).
// Wave tile 32co x 112w, acc[2][7] f32x4. A-fragments register-resident.
__global__ __launch_bounds__(512, 2) void conv3(
    const unsigned short* __restrict__ xp, const unsigned short* __restrict__ wr,
    const float* __restrict__ bias, float* __restrict__ out)
{
    extern __shared__ __align__(16) unsigned short ring[];  // [6][7296] shorts + bounce floats
    float* bounce = (float*)ring + 6 * ROWBUF_SHORTS / 2;   // 8 waves x 1840 floats

    int bid = blockIdx.x;
    int swz = (bid & 7) * 32 + (bid >> 3);     // bijective over 256, XCD-chunked
    int n = swz >> 4;
    int rem = swz & 15;
    int wseg = rem & 1;
    int strip = rem >> 1;
    int ho0 = strip * 28;

    int tid = threadIdx.x, lane = tid & 63, wid = tid >> 6;
    int hr = wid & 1, mq = wid >> 1;
    int lrow = lane & 15, lk = lane >> 4;

    const unsigned short* xpn = xp + (size_t)n * NS_;

    // ---- hoisted A-fragments: step-invariant, load once (36 x 16B/lane) ----
    bf16x8 A[2][9][2];
    #pragma unroll
    for (int ch = 0; ch < 2; ++ch)
        #pragma unroll
        for (int t = 0; t < 9; ++t)
            #pragma unroll
            for (int mf = 0; mf < 2; ++mf) {
                size_t ai = ((size_t)(t * 128 + mq * 32 + mf * 16 + lrow)) * 64
                          + (size_t)(ch * 32 + lk * 8);
                A[ch][t][mf] = *(const bf16x8*)(wr + ai);
            }

    // stage one xp row (912 x 16B chunks) into its ring slot; dst linear in tid.
    auto stage_row = [&](int hp) {
        const unsigned short* srow = xpn + (size_t)hp * HPS_ + (size_t)(wseg * 112) * 8;
        unsigned short* dbase = ring + (size_t)(hp % 6) * ROWBUF_SHORTS;
        int idx = tid;
        {
            int cb = idx / 114, wp = idx - cb * 114;
            __builtin_amdgcn_global_load_lds(
                (const __attribute__((address_space(1))) void*)(srow + (size_t)cb * CBS_ + (size_t)wp * 8),
                (__attribute__((address_space(3))) void*)(dbase + (size_t)idx * 8), 16, 0, 0);
        }
        idx = 512 + tid;
        if (idx < 912) {
            int cb = idx / 114, wp = idx - cb * 114;
            __builtin_amdgcn_global_load_lds(
                (const __attribute__((address_space(1))) void*)(srow + (size_t)cb * CBS_ + (size_t)wp * 8),
                (__attribute__((address_space(3))) void*)(dbase + (size_t)idx * 8), 16, 0, 0);
        }
    };

    // prologue: rows ho0..ho0+3
    stage_row(ho0); stage_row(ho0 + 1); stage_row(ho0 + 2); stage_row(ho0 + 3);
    __syncthreads();

    #pragma unroll 1
    for (int i = 0; i < 14; ++i) {
        int ho = ho0 + 2 * i;

        // 1) prefetch next step's two new rows into the (dead) slots
        if (i < 13) { stage_row(ho + 4); stage_row(ho + 5); }

        // 2) compute: 2 ci-halves x 9 taps on rows ho..ho+3 (staged last step)
        f32x4 acc[2][7];
        #pragma unroll
        for (int a = 0; a < 2; ++a)
            #pragma unroll
            for (int b2 = 0; b2 < 7; ++b2)
                #pragma unroll
                for (int k = 0; k < 4; ++k)
                    acc[a][b2][k] = 0.0f;

        #pragma unroll
        for (int ch = 0; ch < 2; ++ch) {
            #pragma unroll
            for (int t = 0; t < 9; ++t) {
                int kh = t / 3, kw = t - kh * 3;
                int slot = (ho + hr + kh) % 6;
                int rb = slot * ROWBUF_SHORTS + ((ch * 4 + lk) * 114) * 8;
                int wb = lrow + kw;
                #pragma unroll
                for (int nf = 0; nf < 7; ++nf) {
                    bf16x8 bfr = *(const bf16x8*)(ring + rb + (size_t)(wb + nf * 16) * 8);
                    acc[0][nf] = __builtin_amdgcn_mfma_f32_16x16x32_bf16(A[ch][t][0], bfr, acc[0][nf], 0, 0, 0);
                    acc[1][nf] = __builtin_amdgcn_mfma_f32_16x16x32_bf16(A[ch][t][1], bfr, acc[1][nf], 0, 0, 0);
                }
            }
        }

        // 3) epilogue: per-wave LDS bounce -> contiguous float4 stores
        //    bounce layout [lk s464][r s112][w 112]: lk byte-stride 1856 ≡ 64 mod 128
        //    -> balanced 2-way bank access on writes (free).
        float* lf = bounce + wid * BOUNCE_WAVE_F;
        int h = ho + hr;
        #pragma unroll
        for (int mf = 0; mf < 2; ++mf) {
            float bv[4];
            #pragma unroll
            for (int r = 0; r < 4; ++r)
                bv[r] = bias[mq * 32 + mf * 16 + lk * 4 + r];
            float* wbase = lf + lk * 464 + lrow;
            #pragma unroll
            for (int r = 0; r < 4; ++r)
                #pragma unroll
                for (int nf = 0; nf < 7; ++nf)
                    wbase[r * 112 + nf * 16] = acc[mf][nf][r] + bv[r];
            // wave-local: DS ops in-order per wave
            #pragma unroll
            for (int j = 0; j < 7; ++j) {
                int idx4 = j * 64 + lane;          // 448 float4 per wave
                int col = idx4 / 28;               // co_local 0..15
                int w4  = idx4 - col * 28;
                f32x4 v = *(const f32x4*)(lf + (col >> 2) * 464 + (col & 3) * 112 + w4 * 4);
                size_t ob = (((size_t)n * CO_ + mq * 32 + mf * 16 + col) * H_ + h) * W_
                          + wseg * 112 + w4 * 4;
                *(f32x4*)(out + ob) = v;
            }
        }

        // 4) counted barrier: per-wave FIFO = [<=4 ring DMAs][14 stores];
        //    vmcnt(14) drains all DMAs (publishes ring) while the 14 output
        //    stores stay in flight and overlap the next step's compute.
        __builtin_amdgcn_sched_barrier(0);
        asm volatile("s_waitcnt vmcnt(14) lgkmcnt(0)" ::: "memory");
        __builtin_amdgcn_s_barrier();
        __builtin_amdgcn_sched_barrier(0);
    }
}

// ---------------- fallback (used only if dynamic-LDS attribute fails) ----------------
__global__ __launch_bounds__(256, 2) void conv2(
    const unsigned short* __restrict__ xp, const unsigned short* __restrict__ wr,
    const float* __restrict__ bias, float* __restrict__ out)
{
    __shared__ __align__(16) unsigned short xs[4 * 8 * 114 * 8];

    int bid = blockIdx.x;
    int swz = (bid & 7) * 448 + (bid >> 3);
    int n = swz / 224;
    int r2 = swz - n * 224;
    int hblk = r2 >> 1;
    int wseg = r2 & 1;
    int h0 = hblk * 2;

    int tid = threadIdx.x, lane = tid & 63, wid = tid >> 6;
    int hr = wid & 1, mh = wid >> 1;
    int lrow = lane & 15, lk = lane >> 4;

    f32x4 acc[4][7];
    #pragma unroll
    for (int a = 0; a < 4; ++a)
        #pragma unroll
        for (int b2 = 0; b2 < 7; ++b2)
            #pragma unroll
            for (int k = 0; k < 4; ++k)
                acc[a][b2][k] = 0.0f;

    const unsigned short* xpn = xp + (size_t)n * NS_;

    #pragma unroll
    for (int it = 0; it < 14; ++it) {
        int idx = it * 256 + tid;
        int wp = idx % 114;
        int rc = idx / 114;
        const unsigned short* src = xpn + (size_t)(h0 + (rc >> 3)) * HPS_
                                  + (size_t)(rc & 7) * CBS_ + (size_t)(wseg * 112 + wp) * 8;
        __builtin_amdgcn_global_load_lds(
            (const __attribute__((address_space(1))) void*)src,
            (__attribute__((address_space(3))) void*)(xs + (size_t)idx * 8), 16, 0, 0);
    }
    if (tid < 64) {
        int idx = 3584 + tid;
        int wp = idx % 114;
        int rc = idx / 114;
        const unsigned short* src = xpn + (size_t)(h0 + (rc >> 3)) * HPS_
                                  + (size_t)(rc & 7) * CBS_ + (size_t)(wseg * 112 + wp) * 8;
        __builtin_amdgcn_global_load_lds(
            (const __attribute__((address_space(1))) void*)src,
            (__attribute__((address_space(3))) void*)(xs + (size_t)idx * 8), 16, 0, 0);
    }
    __syncthreads();

    #pragma unroll
    for (int ch = 0; ch < 2; ++ch) {
        #pragma unroll
        for (int t = 0; t < 9; ++t) {
            int kh = t / 3, kw = t - kh * 3;
            bf16x8 afr[4];
            #pragma unroll
            for (int mf = 0; mf < 4; ++mf) {
                size_t ai = ((size_t)(t * 128 + mh * 64 + mf * 16 + lrow)) * 64
                          + (size_t)(ch * 32 + lk * 8);
                afr[mf] = *(const bf16x8*)(wr + ai);
            }
            int rbase = ((hr + kh) * 8 + ch * 4 + lk) * 114;
            int wpb = lrow + kw;
            #pragma unroll
            for (int nf = 0; nf < 7; ++nf) {
                bf16x8 bfr = *(const bf16x8*)(&xs[(size_t)(rbase + wpb + nf * 16) * 8]);
                #pragma unroll
                for (int mf = 0; mf < 4; ++mf)
                    acc[mf][nf] = __builtin_amdgcn_mfma_f32_16x16x32_bf16(
                        afr[mf], bfr, acc[mf][nf], 0, 0, 0);
            }
        }
    }

    __syncthreads();
    float* lf = (float*)xs;
    int h = h0 + hr;
    #pragma unroll
    for (int mf = 0; mf < 4; ++mf) {
        float bv[4];
        #pragma unroll
        for (int r = 0; r < 4; ++r)
            bv[r] = bias[mh * 64 + mf * 16 + lk * 4 + r];
        float* wbase = lf + wid * 1808 + lk * 452 + lrow;
        #pragma unroll
        for (int r = 0; r < 4; ++r)
            #pragma unroll
            for (int nf = 0; nf < 7; ++nf)
                wbase[r * 112 + nf * 16] = acc[mf][nf][r] + bv[r];
        #pragma unroll
        for (int j = 0; j < 7; ++j) {
            int idx4 = j * 64 + lane;
            int col = idx4 / 28;
            int w4  = idx4 - col * 28;
            f32x4 v = *(const f32x4*)(lf + wid * 1808 + (col >> 2) * 452 + (col & 3) * 112 + w4 * 4);
            size_t ob = (((size_t)n * CO_ + mh * 64 + mf * 16 + col) * H_ + h) * W_
                      + wseg * 112 + w4 * 4;
            *(f32x4*)(out + ob) = v;
        }
    }
}

extern "C" void kernel_launch(void* const* d_in, const int* in_sizes, int n_in,
                              void* d_out, int out_size, void* d_ws, size_t ws_size,
                              hipStream_t stream) {
    const float* x    = (const float*)d_in[0];
    const float* w    = (const float*)d_in[1];
    const float* bias = (const float*)d_in[2];
    float* out = (float*)d_out;
    unsigned short* wr = (unsigned short*)d_ws;          // 147,456 B
    const size_t xp_bytes = (size_t)N_ * NS_ * 2;        // 104,603,648 B
    const size_t need = 147456 + xp_bytes;

    prep_weight<<<dim3(288), dim3(256), 0, stream>>>(w, wr);
    if (ws_size >= need) {
        unsigned short* xp = wr + 73728;                 // +147,456 B
        prep_x<<<dim3(16 * 226), dim3(256), 0, stream>>>(x, xp);
        hipError_t e = hipFuncSetAttribute(
            reinterpret_cast<const void*>(conv3),
            hipFuncAttributeMaxDynamicSharedMemorySize, CONV3_LDS);
        if (e == hipSuccess) {
            conv3<<<dim3(256), dim3(512), CONV3_LDS, stream>>>(xp, wr, bias, out);
        } else {
            conv2<<<dim3(16 * 112 * 2), dim3(256), 0, stream>>>(xp, wr, bias, out);
        }
    }
}